// Round 12
// baseline (51.305 us; speedup 1.0000x reference)
//
#include <hip/hip_runtime.h>
#include <hip/hip_bf16.h>
#include <math.h>
#include <limits.h>

// Problem constants (fixed by setup_inputs)
#define BS 2
#define NW 5
#define NS 5
#define NQ 5
#define FDIM 64
#define FH 21
#define FW 21
#define NPOS (FH*FW)            // 441
#define NIMG (BS*NW*(NS+NQ))    // 100
#define NQIMG 50
#define IMG_ELEMS (FDIM*NPOS)   // 28224
#define NY (NS*NPOS)            // 2205
#define QROWS 448               // 441 padded to 28*16
#define SROWS 2304              // 144 tiles of 16 rows; rows 2205..2303 zeroed
#define NSLICE 12               // y split: 144 tiles = 12 * 12
#define NT_S 12                 // y-tiles per slice (12.3 KB LDS)
#define NBLK 250
#define NBLK_SIM (NBLK*NSLICE)  // 3000
#define TILE_B 1024             // 16 rows x 64 B (i8) per tile

typedef __attribute__((ext_vector_type(4))) int int4v;

static __device__ __forceinline__ unsigned short f2bf(float x) {
    union { float f; unsigned u; } v; v.f = x;
    unsigned r = v.u + 0x7fffu + ((v.u >> 16) & 1u);
    return (unsigned short)(r >> 16);
}

static __device__ __forceinline__ float bf2f(unsigned short u) {
    union { unsigned u; float f; } v; v.u = ((unsigned)u) << 16;
    return v.f;
}

static __device__ __forceinline__ void gload_lds16(const void* g, void* l) {
    __builtin_amdgcn_global_load_lds((const __attribute__((address_space(1))) void*)g,
                                     (__attribute__((address_space(3))) void*)l, 16, 0, 0);
}

static __device__ __forceinline__ int med3i(int a, int b, int c) {
    int r;
    asm("v_med3_i32 %0, %1, %2, %3" : "=v"(r) : "v"(a), "v"(b), "v"(c));
    return r;
}

// Insert d into sorted int top-3 (a0>=a1>=a2): max + 2x med3 (3 VALU ops)
#define T3I(d, a0, a1, a2) do { \
    int _n0 = ((d) > (a0)) ? (d) : (a0); \
    int _n1 = med3i((d), (a0), (a1)); \
    int _n2 = med3i((d), (a1), (a2)); \
    (a0) = _n0; (a1) = _n1; (a2) = _n2; } while (0)

#define T3I4(p, i) do { \
    T3I((p)[0], t0[i], t1[i], t2[i]); \
    T3I((p)[1], t0[i], t1[i], t2[i]); \
    T3I((p)[2], t0[i], t1[i], t2[i]); \
    T3I((p)[3], t0[i], t1[i], t2[i]); } while (0)

// float top-3 insert for the merge kernel
#define T3F(d, a0, a1, a2) do { \
    float _n0 = fmaxf((d), (a0)); \
    float _n1 = __builtin_amdgcn_fmed3f((d), (a0), (a1)); \
    float _n2 = __builtin_amdgcn_fmed3f((d), (a1), (a2)); \
    (a0) = _n0; (a1) = _n1; (a2) = _n2; } while (0)

// Kernel A: L2-normalize per (img,pos), quantize to i8 (scale 127, RNE).
__global__ __launch_bounds__(256) void dn4_normalize(const float* __restrict__ fm,
                                                     const int* __restrict__ elabel,
                                                     char* __restrict__ Qn,
                                                     char* __restrict__ Sn,
                                                     float* __restrict__ out) {
    int gid = blockIdx.x * blockDim.x + threadIdx.x;
    if (gid < 50) {   // label pass-through: out[250+gid]
        int bb = gid / 25, rem = gid % 25, wq = rem / 5, qi = rem % 5;
        out[250 + gid] = (float)elabel[(bb * NW + wq) * (NS + NQ) + NS + qi];
    }
    if (gid < 3960) { // zero S pad rows 2205..2303: 10 mats x 99 rows x 4 int4
        int mat = gid / 396, rem = gid % 396, rr = rem >> 2, k = rem & 3;
        int4v zv = {0, 0, 0, 0};
        *(int4v*)(Sn + (size_t)mat * (SROWS * FDIM) + (size_t)(NY + rr) * FDIM + k * 16) = zv;
    }
    if (gid >= NIMG * NPOS) return;
    int img = gid / NPOS;
    int pos = gid - img * NPOS;
    const float* src = fm + (size_t)img * IMG_ELEMS + pos;
    float v[FDIM];
    float ss = 0.f;
#pragma unroll
    for (int c = 0; c < FDIM; ++c) {
        float x = src[(size_t)c * NPOS];
        v[c] = x;
        ss += x * x;
    }
    float rn = 127.0f / (sqrtf(ss) + 1e-12f);
    int w[16];
#pragma unroll
    for (int k = 0; k < 16; ++k) {
        int q0 = __float2int_rn(v[4 * k]     * rn);
        int q1 = __float2int_rn(v[4 * k + 1] * rn);
        int q2 = __float2int_rn(v[4 * k + 2] * rn);
        int q3 = __float2int_rn(v[4 * k + 3] * rn);
        w[k] = (q0 & 0xff) | ((q1 & 0xff) << 8) | ((q2 & 0xff) << 16) | (q3 << 24);
    }
    char* dst;
    int i10 = img % 10;
    if (i10 < NS) {
        int bw = img / 10;
        dst = Sn + (size_t)bw * (SROWS * FDIM) + (size_t)(i10 * NPOS + pos) * FDIM;
    } else {
        int qidx = (img / 10) * NQ + (i10 - NS);
        dst = Qn + (size_t)qidx * (QROWS * FDIM) + (size_t)pos * FDIM;
    }
#pragma unroll
    for (int k = 0; k < 4; ++k) {
        int4v t = {w[4 * k], w[4 * k + 1], w[4 * k + 2], w[4 * k + 3]};
        *(int4v*)(dst + 16 * k) = t;
    }
}

// Kernel B: 3000 blocks = (bid, y-slice); 256 threads = 4 waves; wave owns 7
// x-tiles (4*7 = 28). Max-residency geometry: LDS 12.3 KB + VGPR<=64 + 4-wave
// blocks -> 8 blocks/CU = 32 waves/CU (8/SIMD). Proven i8 inner loop: one
// mfma_i32_16x16x64_i8 per (x-tile,y-tile), swizzled LDS, i32 med3 top-3.
__global__ __launch_bounds__(256, 8) void dn4_sim_mfma(const char* __restrict__ Qn,
                                                       const char* __restrict__ Sn,
                                                       unsigned short* __restrict__ gtop3) {
    __shared__ __align__(16) char stile[NT_S][TILE_B];   // 12,288 B

    // XCD swizzle (3000 % 8 == 0 -> simple bijective form)
    int orig = blockIdx.x;
    int unit = (orig & 7) * (NBLK_SIM / 8) + (orig >> 3);
    int bid = unit / NSLICE, ys = unit % NSLICE;

    int w = bid % NW;
    int q = (bid / NW) % (NW * NQ);
    int b = bid / (NW * NW * NQ);
    int wq = q / NQ, qi = q % NQ;
    int qidx = (b * NW + wq) * NQ + qi;

    const char* qbase = Qn + (size_t)qidx * (QROWS * FDIM);
    const char* sbase = Sn + (size_t)(b * NW + w) * (SROWS * FDIM);

    int t = threadIdx.x;
    int lane = t & 63, wv = t >> 6;
    int lo16 = lane & 15, hi4 = lane >> 4;

    // Stage source pre-swizzle: LDS linear [row][c] gets global [row][c ^ ((row>>1)&3)]
    int stg0 = ((lane >> 2) * FDIM) + ((((lane & 3) ^ ((lane >> 3) & 3)) << 4));
    int tbase = ys * NT_S;

    // Cooperative stage: 12 tiles over 4 waves, 1 gload_lds per tile
    for (int i = wv; i < NT_S; i += 4)
        gload_lds16(sbase + (size_t)(tbase + i) * TILE_B + stg0, &stile[i][0]);

    // B fragments (Q): 7 x-tiles; col = lo16 -> x = xt*16+lo16, k = hi4*16..+16
    int4v bq[7];
#pragma unroll
    for (int i = 0; i < 7; ++i) {
        int xt = wv * 7 + i;
        bq[i] = *(const int4v*)(qbase + (size_t)(xt * 16 + lo16) * FDIM + hi4 * 16);
    }

    asm volatile("s_waitcnt vmcnt(0)" ::: "memory");
    __syncthreads();   // the ONLY barrier

    int t0[7], t1[7], t2[7];
#pragma unroll
    for (int i = 0; i < 7; ++i) { t0[i] = INT_MIN; t1[i] = INT_MIN; t2[i] = INT_MIN; }

    int4v zc = {0, 0, 0, 0};

    // Swizzled read: row lo16, want col hi4 -> read hi4 ^ ((lo16>>1)&3)
    int rd = lo16 * FDIM + ((hi4 ^ ((lo16 >> 1) & 3)) << 4);

    int4v ca = *(const int4v*)(&stile[0][0] + rd);
    for (int tt = 0; tt < NT_S; ++tt) {
        int4v na = ca;
        if (tt + 1 < NT_S) na = *(const int4v*)(&stile[tt + 1][0] + rd);
        // 2-deep issue/consume pipeline across the 7 x-tiles
        int4v pA = __builtin_amdgcn_mfma_i32_16x16x64_i8(ca, bq[0], zc, 0, 0, 0);
        int4v pB = __builtin_amdgcn_mfma_i32_16x16x64_i8(ca, bq[1], zc, 0, 0, 0);
        T3I4(pA, 0);
        int4v pC = __builtin_amdgcn_mfma_i32_16x16x64_i8(ca, bq[2], zc, 0, 0, 0);
        T3I4(pB, 1);
        int4v pD = __builtin_amdgcn_mfma_i32_16x16x64_i8(ca, bq[3], zc, 0, 0, 0);
        T3I4(pC, 2);
        int4v pE = __builtin_amdgcn_mfma_i32_16x16x64_i8(ca, bq[4], zc, 0, 0, 0);
        T3I4(pD, 3);
        int4v pF = __builtin_amdgcn_mfma_i32_16x16x64_i8(ca, bq[5], zc, 0, 0, 0);
        T3I4(pE, 4);
        int4v pG = __builtin_amdgcn_mfma_i32_16x16x64_i8(ca, bq[6], zc, 0, 0, 0);
        T3I4(pF, 5);
        T3I4(pG, 6);
        ca = na;
    }

    // Merge top-3 across the 4 y-quarter lane-groups (hi4), scale, write bf16
    const float INV = 1.0f / 16129.0f;   // 1/127^2
#pragma unroll
    for (int i = 0; i < 7; ++i) {
        int a0 = t0[i], a1 = t1[i], a2 = t2[i];
#pragma unroll
        for (int mk = 16; mk <= 32; mk <<= 1) {
            int c0 = __shfl_xor(a0, mk, 64);
            int c1 = __shfl_xor(a1, mk, 64);
            int c2 = __shfl_xor(a2, mk, 64);
            T3I(c0, a0, a1, a2);
            T3I(c1, a0, a1, a2);
            T3I(c2, a0, a1, a2);
        }
        if (hi4 == 0) {
            int x = (wv * 7 + i) * 16 + lo16;
            unsigned short* dst = gtop3 + ((size_t)(bid * QROWS + x) * NSLICE + ys) * 3;
            dst[0] = f2bf((float)a0 * INV);
            dst[1] = f2bf((float)a1 * INV);
            dst[2] = f2bf((float)a2 * INV);
        }
    }
}

// Kernel C: merge the 12 y-slices per (bid,x), sum top-3, block-reduce -> out[bid]
__global__ __launch_bounds__(448) void dn4_merge(const unsigned short* __restrict__ gtop3,
                                                 float* __restrict__ out) {
    __shared__ float red[7];
    int bid = blockIdx.x;
    int t = threadIdx.x, lane = t & 63, wv = t >> 6;
    // 36 bf16 per (bid,x) = 18 dwords (72 B stride, 4B aligned)
    const unsigned* p = (const unsigned*)(gtop3 + (size_t)(bid * QROWS + t) * (NSLICE * 3));
    float v[36];
#pragma unroll
    for (int j = 0; j < 18; ++j) {
        unsigned u = p[j];
        v[2 * j]     = bf2f((unsigned short)(u & 0xffffu));
        v[2 * j + 1] = bf2f((unsigned short)(u >> 16));
    }
    float a0 = v[0], a1 = v[1], a2 = v[2];
#pragma unroll
    for (int j = 3; j < 36; ++j) T3F(v[j], a0, a1, a2);
    float s = (t < NPOS) ? (a0 + a1 + a2) : 0.f;
#pragma unroll
    for (int off = 32; off >= 1; off >>= 1) s += __shfl_xor(s, off, 64);
    if (lane == 0) red[wv] = s;
    __syncthreads();
    if (t == 0) {
        float tot = 0.f;
#pragma unroll
        for (int i = 0; i < 7; ++i) tot += red[i];
        out[bid] = tot;
    }
}

extern "C" void kernel_launch(void* const* d_in, const int* in_sizes, int n_in,
                              void* d_out, int out_size, void* d_ws, size_t ws_size,
                              hipStream_t stream) {
    const float* fm     = (const float*)d_in[0];
    const int*   elabel = (const int*)d_in[1];
    float* out = (float*)d_out;

    char* Qn = (char*)d_ws;                                          // 50*448*64 i8  = 1.43 MB
    char* Sn = Qn + (size_t)NQIMG * QROWS * FDIM;                    // 10*2304*64 i8 = 1.47 MB
    unsigned short* gtop3 = (unsigned short*)(Sn + (size_t)10 * SROWS * FDIM);  // 250*448*36 ush = 8.06 MB

    int nthreads = NIMG * NPOS;
    dn4_normalize<<<(nthreads + 255) / 256, 256, 0, stream>>>(fm, elabel, Qn, Sn, out);
    dn4_sim_mfma<<<NBLK_SIM, 256, 0, stream>>>(Qn, Sn, gtop3);
    dn4_merge<<<NBLK, 448, 0, stream>>>(gtop3, out);
}